// Round 1
// baseline (302.418 us; speedup 1.0000x reference)
//
#include <hip/hip_runtime.h>

#define DEVI __device__ __forceinline__

typedef unsigned short u16;
typedef __attribute__((ext_vector_type(8))) short bf16x8;   // 8 bf16 bit-patterns (4 VGPRs)
typedef __attribute__((ext_vector_type(4))) short bf16x4;
typedef __attribute__((ext_vector_type(4))) float f32x4;

#define Bn 2
#define Tn 2048
#define Hn 16
#define Dn 64
#define Fn 1024
#define Mn 4096  // B*T

// f32 -> bf16, round-to-nearest-even (inputs are finite; no NaN handling needed)
DEVI u16 tobf(float f) {
    unsigned u = __builtin_bit_cast(unsigned, f);
    return (u16)((u + 0x7fffu + ((u >> 16) & 1u)) >> 16);
}

DEVI f32x4 mfma16(bf16x8 a, bf16x8 b, f32x4 c) {
    return __builtin_amdgcn_mfma_f32_16x16x32_bf16(a, b, c, 0, 0, 0);
}

// ---------------------------------------------------------------------------
// RoPE on raw q/k (cos/sin indexed by [t][d], pair (d, d+-32)) + cast to bf16.
// idx bits: [0:3)=d4 (8 groups of 4), [3:7)=h, [7:18)=t, [18]=b, [19]=which(q/k)
// ---------------------------------------------------------------------------
__global__ __launch_bounds__(256) void k_rope(const float* __restrict__ q,
                                              const float* __restrict__ k,
                                              const float* __restrict__ cosb,
                                              const float* __restrict__ sinb,
                                              u16* __restrict__ Aq,
                                              u16* __restrict__ Ak) {
    unsigned idx = blockIdx.x * 256 + threadIdx.x;  // < 1048576
    unsigned which = idx >> 19;
    unsigned r = idx & 0x7FFFFu;
    unsigned d0 = (r & 7u) << 2;
    unsigned h = (r >> 3) & 15u;
    unsigned t = (r >> 7) & 2047u;
    unsigned b = (r >> 18) & 1u;
    const float* src = which ? k : q;
    u16* dst = which ? Ak : Aq;
    size_t base = ((size_t)(b * Tn + t)) * Fn + h * Dn;
    float4 lo = *(const float4*)(src + base + d0);
    float4 hi = *(const float4*)(src + base + d0 + 32);
    float4 cl = *(const float4*)(cosb + (size_t)t * Dn + d0);
    float4 ch = *(const float4*)(cosb + (size_t)t * Dn + d0 + 32);
    float4 sl = *(const float4*)(sinb + (size_t)t * Dn + d0);
    float4 sh = *(const float4*)(sinb + (size_t)t * Dn + d0 + 32);
    bf16x4 olo, ohi;
    olo[0] = (short)tobf(lo.x * cl.x - hi.x * sl.x);
    olo[1] = (short)tobf(lo.y * cl.y - hi.y * sl.y);
    olo[2] = (short)tobf(lo.z * cl.z - hi.z * sl.z);
    olo[3] = (short)tobf(lo.w * cl.w - hi.w * sl.w);
    ohi[0] = (short)tobf(hi.x * ch.x + lo.x * sh.x);
    ohi[1] = (short)tobf(hi.y * ch.y + lo.y * sh.y);
    ohi[2] = (short)tobf(hi.z * ch.z + lo.z * sh.z);
    ohi[3] = (short)tobf(hi.w * ch.w + lo.w * sh.w);
    *(bf16x4*)(dst + base + d0) = olo;
    *(bf16x4*)(dst + base + d0 + 32) = ohi;
}

// ---------------------------------------------------------------------------
// Cast value (4M) + wq/wk/wv/wo (1M each) f32 -> bf16 into one contiguous
// region [Av | Wq | Wk | Wv | Wo]. 8 elems/thread.
// ---------------------------------------------------------------------------
__global__ __launch_bounds__(256) void k_cast(const float* __restrict__ value,
                                              const float* __restrict__ wq,
                                              const float* __restrict__ wk,
                                              const float* __restrict__ wv,
                                              const float* __restrict__ wo,
                                              u16* __restrict__ dst) {
    size_t i8 = ((size_t)blockIdx.x * 256 + threadIdx.x) * 8;  // < 8M
    const size_t M4 = (size_t)4 << 20, M1 = (size_t)1 << 20;
    const float* src;
    size_t off;
    if (i8 < M4)              { src = value; off = i8; }
    else if (i8 < M4 + M1)    { src = wq; off = i8 - M4; }
    else if (i8 < M4 + 2*M1)  { src = wk; off = i8 - M4 - M1; }
    else if (i8 < M4 + 3*M1)  { src = wv; off = i8 - M4 - 2*M1; }
    else                      { src = wo; off = i8 - M4 - 3*M1; }
    float4 a = *(const float4*)(src + off);
    float4 c = *(const float4*)(src + off + 4);
    bf16x8 v;
    v[0] = (short)tobf(a.x); v[1] = (short)tobf(a.y);
    v[2] = (short)tobf(a.z); v[3] = (short)tobf(a.w);
    v[4] = (short)tobf(c.x); v[5] = (short)tobf(c.y);
    v[6] = (short)tobf(c.z); v[7] = (short)tobf(c.w);
    *(bf16x8*)(dst + i8) = v;
}

// ---------------------------------------------------------------------------
// NT GEMM: C[m][n] = (sum_k A[m][k]*W[n][k] + bias[n]) * scale
// M=4096, N=K=1024 fixed. 128x128 tile, BK=32, 256 thr = 4 waves (2x2),
// wave = 64x64 = 4x4 frags of 16x16x32. Reg-staged LDS, single-buffered.
// ---------------------------------------------------------------------------
DEVI void store_out(u16* p, float v) { *p = tobf(v); }
DEVI void store_out(float* p, float v) { *p = v; }

template <typename OUT>
DEVI void gemm_body(const u16* __restrict__ A, const u16* __restrict__ W,
                    const float* __restrict__ bias, OUT* __restrict__ C,
                    float scale, u16* As, u16* Bs) {
    const int tid = threadIdx.x;
    const int lane = tid & 63;
    const int wave = tid >> 6;
    const int l15 = lane & 15, l4 = lane >> 4;
    const int bm = blockIdx.y << 7, bn = blockIdx.x << 7;
    const int wr = (wave >> 1) << 6, wc = (wave & 1) << 6;

    // staging: chunk c (16B = 8 elems) of row-major [128][32]: row=c>>2, col=(c&3)*8
    const int c0 = tid, c1 = tid + 256;
    const u16* A0p = A + (size_t)(bm + (c0 >> 2)) * 1024 + ((c0 & 3) << 3);
    const u16* A1p = A + (size_t)(bm + (c1 >> 2)) * 1024 + ((c1 & 3) << 3);
    const u16* B0p = W + (size_t)(bn + (c0 >> 2)) * 1024 + ((c0 & 3) << 3);
    const u16* B1p = W + (size_t)(bn + (c1 >> 2)) * 1024 + ((c1 & 3) << 3);

    f32x4 acc[4][4] = {};

    bf16x8 ra0 = *(const bf16x8*)(A0p);
    bf16x8 ra1 = *(const bf16x8*)(A1p);
    bf16x8 rb0 = *(const bf16x8*)(B0p);
    bf16x8 rb1 = *(const bf16x8*)(B1p);

    for (int k0 = 0; k0 < 1024; k0 += 32) {
        *(bf16x8*)(As + (c0 << 3)) = ra0;
        *(bf16x8*)(As + (c1 << 3)) = ra1;
        *(bf16x8*)(Bs + (c0 << 3)) = rb0;
        *(bf16x8*)(Bs + (c1 << 3)) = rb1;
        __syncthreads();
        if (k0 + 32 < 1024) {  // prefetch next K-step during compute
            ra0 = *(const bf16x8*)(A0p + k0 + 32);
            ra1 = *(const bf16x8*)(A1p + k0 + 32);
            rb0 = *(const bf16x8*)(B0p + k0 + 32);
            rb1 = *(const bf16x8*)(B1p + k0 + 32);
        }
        bf16x8 af[4], bfr[4];
        #pragma unroll
        for (int m = 0; m < 4; m++)
            af[m] = *(const bf16x8*)(As + (wr + m * 16 + l15) * 32 + (l4 << 3));
        #pragma unroll
        for (int n = 0; n < 4; n++)
            bfr[n] = *(const bf16x8*)(Bs + (wc + n * 16 + l15) * 32 + (l4 << 3));
        #pragma unroll
        for (int m = 0; m < 4; m++)
            #pragma unroll
            for (int n = 0; n < 4; n++)
                acc[m][n] = mfma16(af[m], bfr[n], acc[m][n]);
        __syncthreads();
    }

    // C/D layout: col = lane&15, row = (lane>>4)*4 + j  (m89-verified)
    #pragma unroll
    for (int m = 0; m < 4; m++)
        #pragma unroll
        for (int n = 0; n < 4; n++) {
            const int gcol = bn + wc + n * 16 + l15;
            const float bb = bias[gcol];
            #pragma unroll
            for (int j = 0; j < 4; j++) {
                const int grow = bm + wr + m * 16 + (l4 << 2) + j;
                store_out(C + (size_t)grow * 1024 + gcol, (acc[m][n][j] + bb) * scale);
            }
        }
}

__global__ __launch_bounds__(256) void k_gemm_qkv(
    const u16* A0, const u16* W0, const float* b0, u16* C0,
    const u16* A1, const u16* W1, const float* b1, u16* C1,
    const u16* A2, const u16* W2, const float* b2, u16* C2) {
    __shared__ __align__(16) u16 As[128 * 32];
    __shared__ __align__(16) u16 Bs[128 * 32];
    const int z = blockIdx.z;
    const u16* A = z == 0 ? A0 : (z == 1 ? A1 : A2);
    const u16* W = z == 0 ? W0 : (z == 1 ? W1 : W2);
    const float* bias = z == 0 ? b0 : (z == 1 ? b1 : b2);
    u16* C = z == 0 ? C0 : (z == 1 ? C1 : C2);
    const float scale = z == 0 ? 0.125f : 1.0f;  // fold 1/sqrt(64) into Q
    gemm_body<u16>(A, W, bias, C, scale, As, Bs);
}

__global__ __launch_bounds__(256) void k_gemm_f32(const u16* __restrict__ A,
                                                  const u16* __restrict__ W,
                                                  const float* __restrict__ bias,
                                                  float* __restrict__ C) {
    __shared__ __align__(16) u16 As[128 * 32];
    __shared__ __align__(16) u16 Bs[128 * 32];
    gemm_body<float>(A, W, bias, C, 1.0f, As, Bs);
}

// ---------------------------------------------------------------------------
// V[b][t][h][d] -> Vt[(b,h)][d][t]  (64x64 LDS tiles)
// ---------------------------------------------------------------------------
__global__ __launch_bounds__(256) void k_transpose(const u16* __restrict__ Vp,
                                                   u16* __restrict__ Vt) {
    __shared__ __align__(16) u16 tile[64][72];
    const int tid = threadIdx.x;
    const int bhi = blockIdx.y, t0 = blockIdx.x << 6;
    const int b = bhi >> 4, h = bhi & 15;
    #pragma unroll
    for (int c = tid; c < 1024; c += 256) {
        int r = c >> 4, d0 = (c & 15) << 2;
        bf16x4 val = *(const bf16x4*)(Vp + (size_t)(b * Tn + t0 + r) * Fn + h * Dn + d0);
        *(bf16x4*)(&tile[r][d0]) = val;
    }
    __syncthreads();
    #pragma unroll
    for (int c = tid; c < 1024; c += 256) {
        int d = c >> 4, tt = (c & 15) << 2;
        bf16x4 val;
        val[0] = tile[tt][d]; val[1] = tile[tt + 1][d];
        val[2] = tile[tt + 2][d]; val[3] = tile[tt + 3][d];
        *(bf16x4*)(Vt + ((size_t)bhi * Dn + d) * Tn + t0 + tt) = val;
    }
}

// ---------------------------------------------------------------------------
// Flash attention, non-causal. Grid (16 q-tiles, 32 bh), 256 thr = 4 waves.
// Wave owns 32 Q rows (2 m-frags). KV tile = 64. No barriers (per-wave work).
// Q is pre-scaled by 1/8. K frags and Vt frags read from global (L2-resident).
// P round-trips per-wave LDS (stride 72 -> only 2-way bank aliasing).
// ---------------------------------------------------------------------------
__global__ __launch_bounds__(256) void k_attn(const u16* __restrict__ Qp,
                                              const u16* __restrict__ Kp,
                                              const u16* __restrict__ Vt,
                                              u16* __restrict__ Oa) {
    const int tid = threadIdx.x, wave = tid >> 6, lane = tid & 63;
    const int l15 = lane & 15, l4 = lane >> 4;
    const int bh = blockIdx.y, b = bh >> 4, h = bh & 15;
    const int q0 = blockIdx.x * 128 + wave * 32;

    __shared__ __align__(16) u16 Plds[4][32 * 72];
    u16* P = Plds[wave];

    // Q A-frags: row = lane&15 (+16*m), k contiguous-8 at (lane>>4)*8 (+32*kk)
    bf16x8 aq[2][2];
    #pragma unroll
    for (int m = 0; m < 2; m++)
        #pragma unroll
        for (int kk = 0; kk < 2; kk++) {
            size_t row = (size_t)b * Tn + q0 + m * 16 + l15;
            aq[m][kk] = *(const bf16x8*)(Qp + row * Fn + h * Dn + kk * 32 + (l4 << 3));
        }

    f32x4 o[2][4] = {};
    float mrun[2][4], lrun[2][4];
    #pragma unroll
    for (int m = 0; m < 2; m++)
        #pragma unroll
        for (int j = 0; j < 4; j++) { mrun[m][j] = -1e30f; lrun[m][j] = 0.f; }

    const u16* Kb = Kp + (size_t)b * Tn * Fn + h * Dn;
    const u16* Vb = Vt + (size_t)bh * Dn * Tn;

    #pragma unroll 1
    for (int kv0 = 0; kv0 < Tn; kv0 += 64) {
        // S = Q K^T (Q pre-scaled)
        f32x4 s[2][4] = {};
        #pragma unroll
        for (int n = 0; n < 4; n++) {
            const u16* kr = Kb + (size_t)(kv0 + n * 16 + l15) * Fn;
            #pragma unroll
            for (int kk = 0; kk < 2; kk++) {
                bf16x8 bk = *(const bf16x8*)(kr + kk * 32 + (l4 << 3));
                s[0][n] = mfma16(aq[0][kk], bk, s[0][n]);
                s[1][n] = mfma16(aq[1][kk], bk, s[1][n]);
            }
        }
        // online softmax; row (m,j) lives in the 16 lanes sharing l4
        #pragma unroll
        for (int m = 0; m < 2; m++)
            #pragma unroll
            for (int j = 0; j < 4; j++) {
                float r = fmaxf(fmaxf(s[m][0][j], s[m][1][j]),
                                fmaxf(s[m][2][j], s[m][3][j]));
                #pragma unroll
                for (int off = 1; off < 16; off <<= 1)
                    r = fmaxf(r, __shfl_xor(r, off, 64));
                float mn = fmaxf(mrun[m][j], r);
                float sc = __expf(mrun[m][j] - mn);
                float ps = 0.f;
                #pragma unroll
                for (int n = 0; n < 4; n++) {
                    float p = __expf(s[m][n][j] - mn);
                    ps += p;
                    P[(m * 16 + l4 * 4 + j) * 72 + n * 16 + l15] = tobf(p);
                }
                #pragma unroll
                for (int off = 1; off < 16; off <<= 1)
                    ps += __shfl_xor(ps, off, 64);
                lrun[m][j] = lrun[m][j] * sc + ps;
                mrun[m][j] = mn;
                o[m][0][j] *= sc; o[m][1][j] *= sc;
                o[m][2][j] *= sc; o[m][3][j] *= sc;
            }
        // O += P V : A-frag from P LDS, B-frag from Vt (k contiguous in t)
        #pragma unroll
        for (int kk = 0; kk < 2; kk++) {
            bf16x8 pa0 = *(const bf16x8*)(P + (0 + l15) * 72 + kk * 32 + (l4 << 3));
            bf16x8 pa1 = *(const bf16x8*)(P + (16 + l15) * 72 + kk * 32 + (l4 << 3));
            #pragma unroll
            for (int nd = 0; nd < 4; nd++) {
                bf16x8 bv = *(const bf16x8*)(Vb + (size_t)(nd * 16 + l15) * Tn +
                                             kv0 + kk * 32 + (l4 << 3));
                o[0][nd] = mfma16(pa0, bv, o[0][nd]);
                o[1][nd] = mfma16(pa1, bv, o[1][nd]);
            }
        }
    }
    // epilogue: divide by row sum, write bf16
    #pragma unroll
    for (int m = 0; m < 2; m++)
        #pragma unroll
        for (int nd = 0; nd < 4; nd++)
            #pragma unroll
            for (int j = 0; j < 4; j++) {
                size_t row = (size_t)b * Tn + q0 + m * 16 + (l4 << 2) + j;
                Oa[row * Fn + h * Dn + nd * 16 + l15] =
                    tobf(o[m][nd][j] / lrun[m][j]);
            }
}

// ---------------------------------------------------------------------------
extern "C" void kernel_launch(void* const* d_in, const int* in_sizes, int n_in,
                              void* d_out, int out_size, void* d_ws, size_t ws_size,
                              hipStream_t stream) {
    const float* q    = (const float*)d_in[0];
    const float* k    = (const float*)d_in[1];
    const float* v    = (const float*)d_in[2];
    const float* cosb = (const float*)d_in[3];
    const float* sinb = (const float*)d_in[4];
    const float* wq   = (const float*)d_in[5];
    const float* wk   = (const float*)d_in[6];
    const float* wv   = (const float*)d_in[7];
    const float* wo   = (const float*)d_in[8];
    const float* bq   = (const float*)d_in[9];
    const float* bk   = (const float*)d_in[10];
    const float* bv   = (const float*)d_in[11];
    const float* bo   = (const float*)d_in[12];

    char* ws = (char*)d_ws;
    const size_t MB8 = (size_t)8 << 20;
    u16* Aq  = (u16*)(ws);             // 8MB; reused as Oa after QKV GEMM
    u16* Ak  = (u16*)(ws + MB8);       // 8MB; reused as Vt after QKV GEMM
    u16* Av  = (u16*)(ws + 2 * MB8);   // 8MB, contiguous with weights below
    u16* Wq  = (u16*)(ws + 3 * MB8);
    u16* Wk  = (u16*)(ws + 3 * MB8 + ((size_t)2 << 20));
    u16* Wv  = (u16*)(ws + 3 * MB8 + ((size_t)4 << 20));
    u16* Wo  = (u16*)(ws + 3 * MB8 + ((size_t)6 << 20));
    u16* Qp  = (u16*)(ws + 4 * MB8);
    u16* Kp  = (u16*)(ws + 5 * MB8);
    u16* Vp  = (u16*)(ws + 6 * MB8);   // total 56MB
    u16* Oa  = Aq;
    u16* Vtr = Ak;

    k_rope<<<4096, 256, 0, stream>>>(q, k, cosb, sinb, Aq, Ak);
    k_cast<<<4096, 256, 0, stream>>>(v, wq, wk, wv, wo, Av);
    k_gemm_qkv<<<dim3(8, 32, 3), 256, 0, stream>>>(Aq, Wq, bq, Qp,
                                                   Ak, Wk, bk, Kp,
                                                   Av, Wv, bv, Vp);
    k_transpose<<<dim3(32, 32), 256, 0, stream>>>(Vp, Vtr);
    k_attn<<<dim3(16, 32), 256, 0, stream>>>(Qp, Kp, Vtr, Oa);
    k_gemm_f32<<<dim3(8, 32), 256, 0, stream>>>(Oa, Wo, bo, (float*)d_out);
}

// Round 2
// 207.951 us; speedup vs baseline: 1.4543x; 1.4543x over previous
//
#include <hip/hip_runtime.h>

#define DEVI __device__ __forceinline__

typedef unsigned short u16;
typedef unsigned int u32;
typedef __attribute__((ext_vector_type(8))) short bf16x8;   // 8 bf16 bit-patterns (4 VGPRs)
typedef __attribute__((ext_vector_type(4))) short bf16x4;
typedef __attribute__((ext_vector_type(4))) float f32x4;

#define Bn 2
#define Tn 2048
#define Hn 16
#define Dn 64
#define Fn 1024

// f32 -> bf16, round-to-nearest-even
DEVI u16 tobf(float f) {
    unsigned u = __builtin_bit_cast(unsigned, f);
    return (u16)((u + 0x7fffu + ((u >> 16) & 1u)) >> 16);
}

DEVI f32x4 mfma16(bf16x8 a, bf16x8 b, f32x4 c) {
    return __builtin_amdgcn_mfma_f32_16x16x32_bf16(a, b, c, 0, 0, 0);
}

// async global->LDS, 16B per lane. LDS dest must be wave-uniform base + lane*16.
DEVI void gload_lds16(const u16* g, u16* l) {
    __builtin_amdgcn_global_load_lds(
        (const __attribute__((address_space(1))) void*)g,
        (__attribute__((address_space(3))) void*)l, 16, 0, 0);
}

// ---------------------------------------------------------------------------
// RoPE on raw q/k (cos/sin indexed by [t][d], pair (d, d+-32)) + cast to bf16.
// ---------------------------------------------------------------------------
__global__ __launch_bounds__(256) void k_rope(const float* __restrict__ q,
                                              const float* __restrict__ k,
                                              const float* __restrict__ cosb,
                                              const float* __restrict__ sinb,
                                              u16* __restrict__ Aq,
                                              u16* __restrict__ Ak) {
    unsigned idx = blockIdx.x * 256 + threadIdx.x;  // < 1048576
    unsigned which = idx >> 19;
    unsigned r = idx & 0x7FFFFu;
    unsigned d0 = (r & 7u) << 2;
    unsigned h = (r >> 3) & 15u;
    unsigned t = (r >> 7) & 2047u;
    unsigned b = (r >> 18) & 1u;
    const float* src = which ? k : q;
    u16* dst = which ? Ak : Aq;
    size_t base = ((size_t)(b * Tn + t)) * Fn + h * Dn;
    float4 lo = *(const float4*)(src + base + d0);
    float4 hi = *(const float4*)(src + base + d0 + 32);
    float4 cl = *(const float4*)(cosb + (size_t)t * Dn + d0);
    float4 ch = *(const float4*)(cosb + (size_t)t * Dn + d0 + 32);
    float4 sl = *(const float4*)(sinb + (size_t)t * Dn + d0);
    float4 sh = *(const float4*)(sinb + (size_t)t * Dn + d0 + 32);
    bf16x4 olo, ohi;
    olo[0] = (short)tobf(lo.x * cl.x - hi.x * sl.x);
    olo[1] = (short)tobf(lo.y * cl.y - hi.y * sl.y);
    olo[2] = (short)tobf(lo.z * cl.z - hi.z * sl.z);
    olo[3] = (short)tobf(lo.w * cl.w - hi.w * sl.w);
    ohi[0] = (short)tobf(hi.x * ch.x + lo.x * sh.x);
    ohi[1] = (short)tobf(hi.y * ch.y + lo.y * sh.y);
    ohi[2] = (short)tobf(hi.z * ch.z + lo.z * sh.z);
    ohi[3] = (short)tobf(hi.w * ch.w + lo.w * sh.w);
    *(bf16x4*)(dst + base + d0) = olo;
    *(bf16x4*)(dst + base + d0 + 32) = ohi;
}

// ---------------------------------------------------------------------------
// Cast value (4M) + wq/wk/wv/wo (1M each) f32 -> bf16, contiguous region.
// ---------------------------------------------------------------------------
__global__ __launch_bounds__(256) void k_cast(const float* __restrict__ value,
                                              const float* __restrict__ wq,
                                              const float* __restrict__ wk,
                                              const float* __restrict__ wv,
                                              const float* __restrict__ wo,
                                              u16* __restrict__ dst) {
    size_t i8 = ((size_t)blockIdx.x * 256 + threadIdx.x) * 8;  // < 8M
    const size_t M4 = (size_t)4 << 20, M1 = (size_t)1 << 20;
    const float* src;
    size_t off;
    if (i8 < M4)              { src = value; off = i8; }
    else if (i8 < M4 + M1)    { src = wq; off = i8 - M4; }
    else if (i8 < M4 + 2*M1)  { src = wk; off = i8 - M4 - M1; }
    else if (i8 < M4 + 3*M1)  { src = wv; off = i8 - M4 - 2*M1; }
    else                      { src = wo; off = i8 - M4 - 3*M1; }
    float4 a = *(const float4*)(src + off);
    float4 c = *(const float4*)(src + off + 4);
    bf16x8 v;
    v[0] = (short)tobf(a.x); v[1] = (short)tobf(a.y);
    v[2] = (short)tobf(a.z); v[3] = (short)tobf(a.w);
    v[4] = (short)tobf(c.x); v[5] = (short)tobf(c.y);
    v[6] = (short)tobf(c.z); v[7] = (short)tobf(c.w);
    *(bf16x8*)(dst + i8) = v;
}

// ---------------------------------------------------------------------------
// NT GEMM: C[m][n] = (sum_k A[m][k]*W[n][k] + bias[n]) * scale
// M=4096, N=K=1024. 128x128 tile, BK=32, 4 waves (2x2), 4x4 frags/wave.
// m97-style: global_load_lds width-16 staging, single-buffered.
// ---------------------------------------------------------------------------
DEVI void store_out(u16* p, float v) { *p = tobf(v); }
DEVI void store_out(float* p, float v) { *p = v; }

template <typename OUT>
DEVI void gemm_body(const u16* __restrict__ A, const u16* __restrict__ W,
                    const float* __restrict__ bias, OUT* __restrict__ C,
                    float scale, u16* As, u16* Bs) {
    const int tid = threadIdx.x;
    const int lane = tid & 63;
    const int wave = tid >> 6;
    const int l15 = lane & 15, l4 = lane >> 4;
    const int bm = blockIdx.y << 7, bn = blockIdx.x << 7;
    const int wr = (wave >> 1) << 6, wc = (wave & 1) << 6;

    // chunk c (16B) of row-major [128][32]: row=c>>2, col=(c&3)*8; LDS byte off = c*16
    const int c0 = tid, c1 = tid + 256;
    const u16* A0p = A + (size_t)(bm + (c0 >> 2)) * 1024 + ((c0 & 3) << 3);
    const u16* A1p = A + (size_t)(bm + (c1 >> 2)) * 1024 + ((c1 & 3) << 3);
    const u16* B0p = W + (size_t)(bn + (c0 >> 2)) * 1024 + ((c0 & 3) << 3);
    const u16* B1p = W + (size_t)(bn + (c1 >> 2)) * 1024 + ((c1 & 3) << 3);
    u16* Ad0 = As + (c0 << 3);
    u16* Ad1 = As + (c1 << 3);
    u16* Bd0 = Bs + (c0 << 3);
    u16* Bd1 = Bs + (c1 << 3);

    f32x4 acc[4][4] = {};

    for (int k0 = 0; k0 < 1024; k0 += 32) {
        gload_lds16(A0p + k0, Ad0);
        gload_lds16(A1p + k0, Ad1);
        gload_lds16(B0p + k0, Bd0);
        gload_lds16(B1p + k0, Bd1);
        __syncthreads();  // drains vmcnt -> LDS tile ready
        bf16x8 af[4], bfr[4];
        #pragma unroll
        for (int m = 0; m < 4; m++)
            af[m] = *(const bf16x8*)(As + (wr + m * 16 + l15) * 32 + (l4 << 3));
        #pragma unroll
        for (int n = 0; n < 4; n++)
            bfr[n] = *(const bf16x8*)(Bs + (wc + n * 16 + l15) * 32 + (l4 << 3));
        #pragma unroll
        for (int m = 0; m < 4; m++)
            #pragma unroll
            for (int n = 0; n < 4; n++)
                acc[m][n] = mfma16(af[m], bfr[n], acc[m][n]);
        __syncthreads();  // all waves done reading before overwrite
    }

    // C/D layout: col = lane&15, row = (lane>>4)*4 + j  (m89-verified)
    #pragma unroll
    for (int m = 0; m < 4; m++)
        #pragma unroll
        for (int n = 0; n < 4; n++) {
            const int gcol = bn + wc + n * 16 + l15;
            const float bb = bias[gcol];
            #pragma unroll
            for (int j = 0; j < 4; j++) {
                const int grow = bm + wr + m * 16 + (l4 << 2) + j;
                store_out(C + (size_t)grow * 1024 + gcol, (acc[m][n][j] + bb) * scale);
            }
        }
}

__global__ __launch_bounds__(256) void k_gemm_qkv(
    const u16* A0, const u16* W0, const float* b0, u16* C0,
    const u16* A1, const u16* W1, const float* b1, u16* C1,
    const u16* A2, const u16* W2, const float* b2, u16* C2) {
    __shared__ __align__(16) u16 As[128 * 32];
    __shared__ __align__(16) u16 Bs[128 * 32];
    const int z = blockIdx.z;
    const u16* A = z == 0 ? A0 : (z == 1 ? A1 : A2);
    const u16* W = z == 0 ? W0 : (z == 1 ? W1 : W2);
    const float* bias = z == 0 ? b0 : (z == 1 ? b1 : b2);
    u16* C = z == 0 ? C0 : (z == 1 ? C1 : C2);
    const float scale = z == 0 ? 0.125f : 1.0f;  // fold 1/sqrt(64) into Q
    gemm_body<u16>(A, W, bias, C, scale, As, Bs);
}

__global__ __launch_bounds__(256) void k_gemm_f32(const u16* __restrict__ A,
                                                  const u16* __restrict__ W,
                                                  const float* __restrict__ bias,
                                                  float* __restrict__ C) {
    __shared__ __align__(16) u16 As[128 * 32];
    __shared__ __align__(16) u16 Bs[128 * 32];
    gemm_body<float>(A, W, bias, C, 1.0f, As, Bs);
}

// ---------------------------------------------------------------------------
// V[b][t][h][d] -> Vt[(b,h)][d][t]
// ---------------------------------------------------------------------------
__global__ __launch_bounds__(256) void k_transpose(const u16* __restrict__ Vp,
                                                   u16* __restrict__ Vt) {
    __shared__ __align__(16) u16 tile[64][72];
    const int tid = threadIdx.x;
    const int bhi = blockIdx.y, t0 = blockIdx.x << 6;
    const int b = bhi >> 4, h = bhi & 15;
    #pragma unroll
    for (int c = tid; c < 1024; c += 256) {
        int r = c >> 4, d0 = (c & 15) << 2;
        bf16x4 val = *(const bf16x4*)(Vp + (size_t)(b * Tn + t0 + r) * Fn + h * Dn + d0);
        *(bf16x4*)(&tile[r][d0]) = val;
    }
    __syncthreads();
    #pragma unroll
    for (int c = tid; c < 1024; c += 256) {
        int d = c >> 4, tt = (c & 15) << 2;
        bf16x4 val;
        val[0] = tile[tt][d]; val[1] = tile[tt + 1][d];
        val[2] = tile[tt + 2][d]; val[3] = tile[tt + 3][d];
        *(bf16x4*)(Vt + ((size_t)bhi * Dn + d) * Tn + t0 + tt) = val;
    }
}

// ---------------------------------------------------------------------------
// Flash attention, non-causal, SWAPPED-operand form.
// Grid (16 q-tiles, 32 bh), 4 waves/block, wave owns 32 q rows, KV tile 64.
// S^T = mfma(K, Q): lane owns q = lane&15 (per mq), 16 kv values in-register
//   -> softmax reduce = in-reg tree + 2 shfl_xor (16, 32).
// P packed to bf16 pairs, 8 ds_write_b64 per tile; PV swapped: O^T = mfma(Vt, P).
// ---------------------------------------------------------------------------
__global__ __launch_bounds__(256) void k_attn(const u16* __restrict__ Qp,
                                              const u16* __restrict__ Kp,
                                              const u16* __restrict__ Vt,
                                              u16* __restrict__ Oa) {
    const int tid = threadIdx.x, wave = tid >> 6, lane = tid & 63;
    const int l15 = lane & 15, l4 = lane >> 4;
    const int bh = blockIdx.y, b = bh >> 4, h = bh & 15;
    const int q0 = blockIdx.x * 128 + wave * 32;

    __shared__ __align__(16) u16 Plds[4][32 * 72];
    u16* P = Plds[wave];

    // Q as B-frag (pre-scaled by 1/8): lane l15 = q row, k contiguous-8 at l4*8
    bf16x8 aq[2][2];
    #pragma unroll
    for (int mq = 0; mq < 2; mq++)
        #pragma unroll
        for (int kk = 0; kk < 2; kk++)
            aq[mq][kk] = *(const bf16x8*)(Qp +
                ((size_t)(b * Tn + q0 + mq * 16 + l15)) * Fn + h * Dn + kk * 32 + (l4 << 3));

    f32x4 o[2][4] = {};                       // O^T: lane q=l15, d = nd*16+l4*4+r
    float mrun[2] = {-1e30f, -1e30f};
    float lrun[2] = {0.f, 0.f};

    const u16* Kb = Kp + (size_t)b * Tn * Fn + h * Dn;
    const u16* Vb = Vt + (size_t)bh * Dn * Tn;

    #pragma unroll 1
    for (int kv0 = 0; kv0 < Tn; kv0 += 64) {
        // S^T[kv][q]: s[mq][n][r] = S[q=mq*16+l15][kv = n*16 + l4*4 + r]
        f32x4 s[2][4] = {};
        #pragma unroll
        for (int n = 0; n < 4; n++) {
            const u16* kr = Kb + (size_t)(kv0 + n * 16 + l15) * Fn;
            #pragma unroll
            for (int kk = 0; kk < 2; kk++) {
                bf16x8 ka = *(const bf16x8*)(kr + kk * 32 + (l4 << 3));
                s[0][n] = mfma16(ka, aq[0][kk], s[0][n]);
                s[1][n] = mfma16(ka, aq[1][kk], s[1][n]);
            }
        }
        // online softmax: per-lane in-register over 16 values, then 2 shfl over l4 groups
        #pragma unroll
        for (int mq = 0; mq < 2; mq++) {
            float tm = s[mq][0][0];
            #pragma unroll
            for (int n = 0; n < 4; n++)
                #pragma unroll
                for (int r = 0; r < 4; r++)
                    tm = fmaxf(tm, s[mq][n][r]);
            tm = fmaxf(tm, __shfl_xor(tm, 16, 64));
            tm = fmaxf(tm, __shfl_xor(tm, 32, 64));
            float mn = fmaxf(mrun[mq], tm);
            float sc = __expf(mrun[mq] - mn);
            mrun[mq] = mn;
            float ps = 0.f;
            #pragma unroll
            for (int n = 0; n < 4; n++) {
                float p0 = __expf(s[mq][n][0] - mn);
                float p1 = __expf(s[mq][n][1] - mn);
                float p2 = __expf(s[mq][n][2] - mn);
                float p3 = __expf(s[mq][n][3] - mn);
                ps += (p0 + p1) + (p2 + p3);
                u32 w0 = (u32)tobf(p0) | ((u32)tobf(p1) << 16);
                u32 w1 = (u32)tobf(p2) | ((u32)tobf(p3) << 16);
                // P[q][kv]: row = mq*16+l15, col = n*16 + l4*4
                *(uint2*)(P + (mq * 16 + l15) * 72 + n * 16 + (l4 << 2)) =
                    make_uint2(w0, w1);
            }
            ps += __shfl_xor(ps, 16, 64);
            ps += __shfl_xor(ps, 32, 64);
            lrun[mq] = lrun[mq] * sc + ps;
            #pragma unroll
            for (int nd = 0; nd < 4; nd++) {
                o[mq][nd][0] *= sc; o[mq][nd][1] *= sc;
                o[mq][nd][2] *= sc; o[mq][nd][3] *= sc;
            }
        }
        // O^T += Vt P^T : first operand Vt rows = d, second P rows = q
        #pragma unroll
        for (int kk = 0; kk < 2; kk++) {
            bf16x8 pb0 = *(const bf16x8*)(P + l15 * 72 + kk * 32 + (l4 << 3));
            bf16x8 pb1 = *(const bf16x8*)(P + (16 + l15) * 72 + kk * 32 + (l4 << 3));
            #pragma unroll
            for (int nd = 0; nd < 4; nd++) {
                bf16x8 va = *(const bf16x8*)(Vb + (size_t)(nd * 16 + l15) * Tn +
                                             kv0 + kk * 32 + (l4 << 3));
                o[0][nd] = mfma16(va, pb0, o[0][nd]);
                o[1][nd] = mfma16(va, pb1, o[1][nd]);
            }
        }
    }
    // epilogue: lane (l15,l4) owns O[q=mq*16+l15][d=nd*16+l4*4 .. +3] -> 8B stores
    #pragma unroll
    for (int mq = 0; mq < 2; mq++) {
        float inv = 1.f / lrun[mq];
        #pragma unroll
        for (int nd = 0; nd < 4; nd++) {
            bf16x4 ov;
            ov[0] = (short)tobf(o[mq][nd][0] * inv);
            ov[1] = (short)tobf(o[mq][nd][1] * inv);
            ov[2] = (short)tobf(o[mq][nd][2] * inv);
            ov[3] = (short)tobf(o[mq][nd][3] * inv);
            *(bf16x4*)(Oa + ((size_t)(b * Tn + q0 + mq * 16 + l15)) * Fn +
                       h * Dn + nd * 16 + (l4 << 2)) = ov;
        }
    }
}

// ---------------------------------------------------------------------------
extern "C" void kernel_launch(void* const* d_in, const int* in_sizes, int n_in,
                              void* d_out, int out_size, void* d_ws, size_t ws_size,
                              hipStream_t stream) {
    const float* q    = (const float*)d_in[0];
    const float* k    = (const float*)d_in[1];
    const float* v    = (const float*)d_in[2];
    const float* cosb = (const float*)d_in[3];
    const float* sinb = (const float*)d_in[4];
    const float* wq   = (const float*)d_in[5];
    const float* wk   = (const float*)d_in[6];
    const float* wv   = (const float*)d_in[7];
    const float* wo   = (const float*)d_in[8];
    const float* bq   = (const float*)d_in[9];
    const float* bk   = (const float*)d_in[10];
    const float* bv   = (const float*)d_in[11];
    const float* bo   = (const float*)d_in[12];

    char* ws = (char*)d_ws;
    const size_t MB8 = (size_t)8 << 20;
    u16* Aq  = (u16*)(ws);             // 8MB; reused as Oa after QKV GEMM
    u16* Ak  = (u16*)(ws + MB8);       // 8MB; reused as Vt after QKV GEMM
    u16* Av  = (u16*)(ws + 2 * MB8);   // 8MB, contiguous with weights below
    u16* Wq  = (u16*)(ws + 3 * MB8);
    u16* Wk  = (u16*)(ws + 3 * MB8 + ((size_t)2 << 20));
    u16* Wv  = (u16*)(ws + 3 * MB8 + ((size_t)4 << 20));
    u16* Wo  = (u16*)(ws + 3 * MB8 + ((size_t)6 << 20));
    u16* Qp  = (u16*)(ws + 4 * MB8);
    u16* Kp  = (u16*)(ws + 5 * MB8);
    u16* Vp  = (u16*)(ws + 6 * MB8);   // total 56MB
    u16* Oa  = Aq;
    u16* Vtr = Ak;

    k_rope<<<4096, 256, 0, stream>>>(q, k, cosb, sinb, Aq, Ak);
    k_cast<<<4096, 256, 0, stream>>>(v, wq, wk, wv, wo, Av);
    k_gemm_qkv<<<dim3(8, 32, 3), 256, 0, stream>>>(Aq, Wq, bq, Qp,
                                                   Ak, Wk, bk, Kp,
                                                   Av, Wv, bv, Vp);
    k_transpose<<<dim3(32, 32), 256, 0, stream>>>(Vp, Vtr);
    k_attn<<<dim3(16, 32), 256, 0, stream>>>(Qp, Kp, Vtr, Oa);
    k_gemm_f32<<<dim3(8, 32), 256, 0, stream>>>(Oa, Wo, bo, (float*)d_out);
}